// Round 1
// baseline (1624.209 us; speedup 1.0000x reference)
//
#include <hip/hip_runtime.h>
#include <math.h>

#define CC 64
#define KK 20
#define DCH 32
#define LOG2E 1.4426950408889634f
#define LN2   0.6931471805599453f
#define LN2PI 1.8378770664093453f
#define BIGN  -1.0e9f

__device__ __forceinline__ float rlane(float v, int l) {
  return __int_as_float(__builtin_amdgcn_readlane(__float_as_int(v), l));
}

// ---------------------------------------------------------------------------
// Setup: precompute wmat = means/var, invvar, per-channel const q2 (base-2),
// transition probabilities P_T[j][i] = exp(log_softmax(masked, axis=0))[i][j],
// init2 (base-2 log-softmax), len2[k][c] (base-2 Poisson length log-probs).
// ---------------------------------------------------------------------------
__global__ void setup_kernel(const float* __restrict__ means,
                             const float* __restrict__ cov,
                             const float* __restrict__ tl,
                             const float* __restrict__ il,
                             const float* __restrict__ plr,
                             float* __restrict__ wmat,
                             float* __restrict__ invvar,
                             float* __restrict__ q2,
                             float* __restrict__ P_T,
                             float* __restrict__ init2,
                             float* __restrict__ len2,
                             int D) {
  int tid = threadIdx.x;  // 256 threads, 1 block
  for (int d = tid; d < D; d += 256) invvar[d] = 1.0f / cov[(size_t)d * D + d];
  __syncthreads();
  for (int i = tid; i < CC * D; i += 256) wmat[i] = means[i] * invvar[i % D];
  if (tid < CC) {
    int c = tid;
    float m2 = 0.f, logdet = 0.f;
    for (int d = 0; d < D; ++d) {
      float mu = means[c * D + d];
      float v  = cov[(size_t)d * D + d];
      m2 += mu * mu / v;
      logdet += logf(v);
    }
    q2[c] = -0.5f * LOG2E * (m2 + logdet + (float)D * LN2PI);
    // column-softmax of masked transition logits -> probabilities
    int j = c;
    float mx = -1e30f;
    for (int i2 = 0; i2 < CC; ++i2) {
      float v = (i2 == j) ? BIGN : tl[i2 * CC + j];
      mx = fmaxf(mx, v);
    }
    float s = 0.f;
    for (int i2 = 0; i2 < CC; ++i2) {
      float v = (i2 == j) ? BIGN : tl[i2 * CC + j];
      s += expf(v - mx);
    }
    float inv = 1.f / s;
    for (int i2 = 0; i2 < CC; ++i2) {
      float v = (i2 == j) ? BIGN : tl[i2 * CC + j];
      P_T[j * CC + i2] = expf(v - mx) * inv;
    }
    // init log-softmax (base-2)
    float mi = -1e30f;
    for (int i2 = 0; i2 < CC; ++i2) mi = fmaxf(mi, il[i2]);
    float si = 0.f;
    for (int i2 = 0; i2 < CC; ++i2) si += expf(il[i2] - mi);
    init2[c] = LOG2E * (il[c] - (mi + logf(si)));
  }
  for (int i = tid; i < KK * CC; i += 256) {
    int k = i / CC, c = i % CC;
    float lr = plr[c];
    float lp = (float)(k + 1) * lr - expf(lr) - lgammaf((float)(k + 2));
    len2[i] = LOG2E * lp;
  }
}

// ---------------------------------------------------------------------------
// Emission: em2[row][c] = log2e * (x.w_c - 0.5*x2) + q2[c]
// 64-row x 64-col tile per block, 4x4 register blocking, 32-wide D chunks.
// ---------------------------------------------------------------------------
__global__ __launch_bounds__(256) void emission_kernel(
    const float* __restrict__ feat,
    const float* __restrict__ wmat,
    const float* __restrict__ invvar,
    const float* __restrict__ q2,
    float* __restrict__ em2,
    int D) {
  __shared__ float xs[64][DCH + 1];
  __shared__ float wsh[64][DCH + 1];
  __shared__ float ivv[DCH];
  __shared__ float q2s[CC];
  int tid = threadIdx.x;
  size_t row0 = (size_t)blockIdx.x * 64;
  if (tid < CC) q2s[tid] = q2[tid];
  int tx = tid & 15, ty = tid >> 4;
  int r0 = ty * 4, c0 = tx * 4;
  int lr_ = tid >> 2;          // 0..63 row for staging
  int lj  = (tid & 3) * 8;     // 0,8,16,24
  float acc00=0,acc01=0,acc02=0,acc03=0;
  float acc10=0,acc11=0,acc12=0,acc13=0;
  float acc20=0,acc21=0,acc22=0,acc23=0;
  float acc30=0,acc31=0,acc32=0,acc33=0;
  float x2a0=0,x2a1=0,x2a2=0,x2a3=0;
  for (int d0 = 0; d0 < D; d0 += DCH) {
    __syncthreads();
    {
      const float4* fx = (const float4*)(feat + (row0 + (size_t)lr_) * D + d0 + lj);
      float4 a = fx[0], b = fx[1];
      xs[lr_][lj+0]=a.x; xs[lr_][lj+1]=a.y; xs[lr_][lj+2]=a.z; xs[lr_][lj+3]=a.w;
      xs[lr_][lj+4]=b.x; xs[lr_][lj+5]=b.y; xs[lr_][lj+6]=b.z; xs[lr_][lj+7]=b.w;
      const float4* fw = (const float4*)(wmat + (size_t)lr_ * D + d0 + lj);
      float4 aw = fw[0], bw = fw[1];
      wsh[lr_][lj+0]=aw.x; wsh[lr_][lj+1]=aw.y; wsh[lr_][lj+2]=aw.z; wsh[lr_][lj+3]=aw.w;
      wsh[lr_][lj+4]=bw.x; wsh[lr_][lj+5]=bw.y; wsh[lr_][lj+6]=bw.z; wsh[lr_][lj+7]=bw.w;
      if (tid < DCH) ivv[tid] = invvar[d0 + tid];
    }
    __syncthreads();
    #pragma unroll
    for (int j = 0; j < DCH; ++j) {
      float iv = ivv[j];
      float xv0 = xs[r0+0][j], xv1 = xs[r0+1][j], xv2 = xs[r0+2][j], xv3 = xs[r0+3][j];
      float wv0 = wsh[c0+0][j], wv1 = wsh[c0+1][j], wv2 = wsh[c0+2][j], wv3 = wsh[c0+3][j];
      x2a0 = fmaf(xv0, xv0*iv, x2a0);
      x2a1 = fmaf(xv1, xv1*iv, x2a1);
      x2a2 = fmaf(xv2, xv2*iv, x2a2);
      x2a3 = fmaf(xv3, xv3*iv, x2a3);
      acc00 = fmaf(xv0, wv0, acc00); acc01 = fmaf(xv0, wv1, acc01);
      acc02 = fmaf(xv0, wv2, acc02); acc03 = fmaf(xv0, wv3, acc03);
      acc10 = fmaf(xv1, wv0, acc10); acc11 = fmaf(xv1, wv1, acc11);
      acc12 = fmaf(xv1, wv2, acc12); acc13 = fmaf(xv1, wv3, acc13);
      acc20 = fmaf(xv2, wv0, acc20); acc21 = fmaf(xv2, wv1, acc21);
      acc22 = fmaf(xv2, wv2, acc22); acc23 = fmaf(xv2, wv3, acc23);
      acc30 = fmaf(xv3, wv0, acc30); acc31 = fmaf(xv3, wv1, acc31);
      acc32 = fmaf(xv3, wv2, acc32); acc33 = fmaf(xv3, wv3, acc33);
    }
  }
  float qa = q2s[c0+0], qb = q2s[c0+1], qc = q2s[c0+2], qd = q2s[c0+3];
  {
    size_t row = row0 + r0 + 0; float h = 0.5f * x2a0; float4 o;
    o.x = LOG2E*(acc00-h)+qa; o.y = LOG2E*(acc01-h)+qb; o.z = LOG2E*(acc02-h)+qc; o.w = LOG2E*(acc03-h)+qd;
    *(float4*)&em2[row*CC + c0] = o;
  }
  {
    size_t row = row0 + r0 + 1; float h = 0.5f * x2a1; float4 o;
    o.x = LOG2E*(acc10-h)+qa; o.y = LOG2E*(acc11-h)+qb; o.z = LOG2E*(acc12-h)+qc; o.w = LOG2E*(acc13-h)+qd;
    *(float4*)&em2[row*CC + c0] = o;
  }
  {
    size_t row = row0 + r0 + 2; float h = 0.5f * x2a2; float4 o;
    o.x = LOG2E*(acc20-h)+qa; o.y = LOG2E*(acc21-h)+qb; o.z = LOG2E*(acc22-h)+qc; o.w = LOG2E*(acc23-h)+qd;
    *(float4*)&em2[row*CC + c0] = o;
  }
  {
    size_t row = row0 + r0 + 3; float h = 0.5f * x2a3; float4 o;
    o.x = LOG2E*(acc30-h)+qa; o.y = LOG2E*(acc31-h)+qb; o.z = LOG2E*(acc32-h)+qc; o.w = LOG2E*(acc33-h)+qd;
    *(float4*)&em2[row*CC + c0] = o;
  }
}

// ---------------------------------------------------------------------------
// Recursion: 1 block = 1 batch, 1 wave of 64 lanes = 64 channels.
// Ring stores g_t = beta_t - CE_t (base-2); doubled ring (64 slots, write
// twice) so history reads use immediate ds offsets. Matvec via P-row in
// registers and readlane broadcast of e = exp2(alpha - max).
// ---------------------------------------------------------------------------
__global__ __launch_bounds__(64, 1) void recur_kernel(
    const float* __restrict__ em2,
    const float* __restrict__ P_T,
    const float* __restrict__ init2,
    const float* __restrict__ len2,
    const int* __restrict__ lengths,
    float* __restrict__ out,
    int N) {
  __shared__ float g[64 * CC];  // [slot][c]
  int b = blockIdx.x;
  int c = threadIdx.x;  // 0..63
  float P[CC];
  #pragma unroll
  for (int j = 0; j < CC; ++j) P[j] = P_T[j * CC + c];  // P[c][j], coalesced per j
  float L[KK];
  #pragma unroll
  for (int k = 0; k < KK; ++k) L[k] = len2[k * CC + c];
  float ivq = init2[c];
  #pragma unroll
  for (int s = 0; s < 64; ++s) g[s * CC + c] = (s == 0 || s == 32) ? ivq : BIGN;
  __syncthreads();
  int len_b = lengths[b];
  const float* em_b = em2 + (size_t)b * N * CC;
  float ce = 0.f;
  float em1  = em_b[c];
  float em2r = (N >= 2) ? em_b[CC + c] : 0.f;
  for (int t = 1; t <= N; ++t) {
    float em = em1;
    em1 = em2r;
    em2r = (t + 2 <= N) ? em_b[(size_t)(t + 1) * CC + c] : 0.f;
    ce += em;
    const float* bp = &g[(t & 31) * CC + c];
    float tk[KK];
    #pragma unroll
    for (int k = 1; k <= KK; ++k) tk[k - 1] = bp[(32 - k) * CC] + L[k - 1];
    float M = tk[0];
    #pragma unroll
    for (int k = 1; k < KK; ++k) M = fmaxf(M, tk[k]);
    float s0 = 0.f, s1 = 0.f, s2 = 0.f, s3 = 0.f;
    #pragma unroll
    for (int k = 0; k < KK; k += 4) {
      s0 += exp2f(tk[k]     - M);
      s1 += exp2f(tk[k + 1] - M);
      s2 += exp2f(tk[k + 2] - M);
      s3 += exp2f(tk[k + 3] - M);
    }
    float alpha = ce + (M + log2f((s0 + s1) + (s2 + s3)));
    if (t == len_b) {
      float Mz = alpha;
      #pragma unroll
      for (int m = 1; m < 64; m <<= 1) Mz = fmaxf(Mz, __shfl_xor(Mz, m, 64));
      float sz = exp2f(alpha - Mz);
      #pragma unroll
      for (int m = 1; m < 64; m <<= 1) sz += __shfl_xor(sz, m, 64);
      if (c == 0) out[b] = LN2 * (Mz + log2f(sz));
    }
    float Ma = alpha;
    #pragma unroll
    for (int m = 1; m < 64; m <<= 1) Ma = fmaxf(Ma, __shfl_xor(Ma, m, 64));
    float e = exp2f(alpha - Ma);
    float a0 = 0.f, a1 = 0.f, a2 = 0.f, a3 = 0.f;
    #pragma unroll
    for (int j = 0; j < CC; j += 4) {
      a0 = fmaf(P[j],     rlane(e, j),     a0);
      a1 = fmaf(P[j + 1], rlane(e, j + 1), a1);
      a2 = fmaf(P[j + 2], rlane(e, j + 2), a2);
      a3 = fmaf(P[j + 3], rlane(e, j + 3), a3);
    }
    float beta = Ma + log2f((a0 + a1) + (a2 + a3));
    float gv = beta - ce;
    float* wp = &g[(t & 31) * CC + c];
    wp[0] = gv;
    wp[32 * CC] = gv;
  }
}

extern "C" void kernel_launch(void* const* d_in, const int* in_sizes, int n_in,
                              void* d_out, int out_size, void* d_ws, size_t ws_size,
                              hipStream_t stream) {
  const float* feat   = (const float*)d_in[0];
  const int*   lens   = (const int*)d_in[1];
  const float* means  = (const float*)d_in[2];
  const float* cov    = (const float*)d_in[3];
  const float* tl     = (const float*)d_in[4];
  const float* il     = (const float*)d_in[5];
  const float* plr    = (const float*)d_in[6];
  int B = in_sizes[1];
  int D = in_sizes[2] / CC;
  int N = in_sizes[0] / (B * D);

  float* ws = (float*)d_ws;
  size_t off = 0;
  float* wmat   = ws + off; off += (size_t)CC * D;
  float* invvar = ws + off; off += D;
  float* q2     = ws + off; off += CC;
  float* P_T    = ws + off; off += CC * CC;
  float* init2  = ws + off; off += CC;
  float* len2   = ws + off; off += KK * CC;
  float* em2    = ws + off; off += (size_t)B * N * CC;

  hipLaunchKernelGGL(setup_kernel, dim3(1), dim3(256), 0, stream,
                     means, cov, tl, il, plr, wmat, invvar, q2, P_T, init2, len2, D);
  hipLaunchKernelGGL(emission_kernel, dim3((B * N) / 64), dim3(256), 0, stream,
                     feat, wmat, invvar, q2, em2, D);
  hipLaunchKernelGGL(recur_kernel, dim3(B), dim3(64), 0, stream,
                     em2, P_T, init2, len2, lens, (float*)d_out, N);
}

// Round 3
// 747.288 us; speedup vs baseline: 2.1735x; 2.1735x over previous
//
#include <hip/hip_runtime.h>
#include <math.h>

#define CC 64
#define KK 20
#define DCH 32
#define LOG2E 1.4426950408889634f
#define LN2   0.6931471805599453f
#define LN2PI 1.8378770664093453f
#define BIGN  -1.0e9f

#if __has_builtin(__builtin_amdgcn_exp2f)
#define EXP2(x) __builtin_amdgcn_exp2f(x)
#else
#define EXP2(x) exp2f(x)
#endif
#if __has_builtin(__builtin_amdgcn_logf)
#define LOG2(x) __builtin_amdgcn_logf(x)
#else
#define LOG2(x) log2f(x)
#endif

typedef _Float16 h2 __attribute__((ext_vector_type(2)));

__device__ __forceinline__ float rlane(float v, int l) {
  return __int_as_float(__builtin_amdgcn_readlane(__float_as_int(v), l));
}

template <int Ctrl, int OldBits>
__device__ __forceinline__ float dpp_mov(float x) {
  return __int_as_float(__builtin_amdgcn_update_dpp(
      OldBits, __float_as_int(x), Ctrl, 0xf, 0xf, false));
}

// full-wave64 max via DPP (row_shr 1/2/4/8 + row_bcast 15/31), then readlane 63
__device__ __forceinline__ float wave_max64(float x) {
  constexpr int NI = (int)0xff800000;  // -inf
  x = fmaxf(x, dpp_mov<0x111, NI>(x));
  x = fmaxf(x, dpp_mov<0x112, NI>(x));
  x = fmaxf(x, dpp_mov<0x114, NI>(x));
  x = fmaxf(x, dpp_mov<0x118, NI>(x));
  x = fmaxf(x, dpp_mov<0x142, NI>(x));
  x = fmaxf(x, dpp_mov<0x143, NI>(x));
  return __int_as_float(__builtin_amdgcn_readlane(__float_as_int(x), 63));
}

__device__ __forceinline__ float wave_sum64(float x) {
  x += dpp_mov<0x111, 0>(x);
  x += dpp_mov<0x112, 0>(x);
  x += dpp_mov<0x114, 0>(x);
  x += dpp_mov<0x118, 0>(x);
  x += dpp_mov<0x142, 0>(x);
  x += dpp_mov<0x143, 0>(x);
  return __int_as_float(__builtin_amdgcn_readlane(__float_as_int(x), 63));
}

// ---------------------------------------------------------------------------
// Setup
// ---------------------------------------------------------------------------
__global__ void setup_kernel(const float* __restrict__ means,
                             const float* __restrict__ cov,
                             const float* __restrict__ tl,
                             const float* __restrict__ il,
                             const float* __restrict__ plr,
                             float* __restrict__ wmat,
                             float* __restrict__ invvar,
                             float* __restrict__ q2,
                             float* __restrict__ P_T,
                             float* __restrict__ init2,
                             float* __restrict__ len2,
                             int D) {
  __shared__ float red[256];
  int tid = threadIdx.x;  // 256 threads, 1 block
  for (int d = tid; d < D; d += 256) invvar[d] = 1.0f / cov[(size_t)d * D + d];
  float lp_ = 0.f;
  for (int d = tid; d < D; d += 256) lp_ += logf(cov[(size_t)d * D + d]);
  red[tid] = lp_;
  __syncthreads();
  for (int s = 128; s > 0; s >>= 1) {
    if (tid < s) red[tid] += red[tid + s];
    __syncthreads();
  }
  float logdet = red[0];
  __syncthreads();
  {
    int c = tid & 63, q = tid >> 6;
    int dq = D / 4;
    float m2p = 0.f;
    for (int d = q * dq; d < (q + 1) * dq; ++d) {
      float mu = means[c * D + d];
      m2p = fmaf(mu * mu, invvar[d], m2p);
    }
    red[tid] = m2p;
  }
  __syncthreads();
  for (int i = tid; i < CC * D; i += 256) wmat[i] = means[i] * invvar[i % D];
  if (tid < CC) {
    int c = tid;
    float m2 = red[c] + red[c + 64] + red[c + 128] + red[c + 192];
    q2[c] = -0.5f * LOG2E * (m2 + logdet + (float)D * LN2PI);
    int j = c;
    float mx = -1e30f;
    for (int i2 = 0; i2 < CC; ++i2) {
      float v = (i2 == j) ? BIGN : tl[i2 * CC + j];
      mx = fmaxf(mx, v);
    }
    float s = 0.f;
    for (int i2 = 0; i2 < CC; ++i2) {
      float v = (i2 == j) ? BIGN : tl[i2 * CC + j];
      s += expf(v - mx);
    }
    float inv = 1.f / s;
    for (int i2 = 0; i2 < CC; ++i2) {
      float v = (i2 == j) ? BIGN : tl[i2 * CC + j];
      P_T[j * CC + i2] = expf(v - mx) * inv;
    }
    float mi = -1e30f;
    for (int i2 = 0; i2 < CC; ++i2) mi = fmaxf(mi, il[i2]);
    float si = 0.f;
    for (int i2 = 0; i2 < CC; ++i2) si += expf(il[i2] - mi);
    init2[c] = LOG2E * (il[c] - (mi + logf(si)));
  }
  for (int i = tid; i < KK * CC; i += 256) {
    int k = i / CC, c = i % CC;
    float lr = plr[c];
    float lp = (float)(k + 1) * lr - expf(lr) - lgammaf((float)(k + 2));
    len2[i] = LOG2E * lp;
  }
}

// ---------------------------------------------------------------------------
// Emission: em2[row][c] = log2e * (x.w_c - 0.5*x2) + q2[c]
// ---------------------------------------------------------------------------
__global__ __launch_bounds__(256) void emission_kernel(
    const float* __restrict__ feat,
    const float* __restrict__ wmat,
    const float* __restrict__ invvar,
    const float* __restrict__ q2,
    float* __restrict__ em2,
    int D) {
  __shared__ float xs[64][DCH + 1];
  __shared__ float wsh[64][DCH + 1];
  __shared__ float ivv[DCH];
  __shared__ float q2s[CC];
  int tid = threadIdx.x;
  size_t row0 = (size_t)blockIdx.x * 64;
  if (tid < CC) q2s[tid] = q2[tid];
  int tx = tid & 15, ty = tid >> 4;
  int r0 = ty * 4, c0 = tx * 4;
  int lr_ = tid >> 2;
  int lj  = (tid & 3) * 8;
  float acc00=0,acc01=0,acc02=0,acc03=0;
  float acc10=0,acc11=0,acc12=0,acc13=0;
  float acc20=0,acc21=0,acc22=0,acc23=0;
  float acc30=0,acc31=0,acc32=0,acc33=0;
  float x2a0=0,x2a1=0,x2a2=0,x2a3=0;
  for (int d0 = 0; d0 < D; d0 += DCH) {
    __syncthreads();
    {
      const float4* fx = (const float4*)(feat + (row0 + (size_t)lr_) * D + d0 + lj);
      float4 a = fx[0], b = fx[1];
      xs[lr_][lj+0]=a.x; xs[lr_][lj+1]=a.y; xs[lr_][lj+2]=a.z; xs[lr_][lj+3]=a.w;
      xs[lr_][lj+4]=b.x; xs[lr_][lj+5]=b.y; xs[lr_][lj+6]=b.z; xs[lr_][lj+7]=b.w;
      const float4* fw = (const float4*)(wmat + (size_t)lr_ * D + d0 + lj);
      float4 aw = fw[0], bw = fw[1];
      wsh[lr_][lj+0]=aw.x; wsh[lr_][lj+1]=aw.y; wsh[lr_][lj+2]=aw.z; wsh[lr_][lj+3]=aw.w;
      wsh[lr_][lj+4]=bw.x; wsh[lr_][lj+5]=bw.y; wsh[lr_][lj+6]=bw.z; wsh[lr_][lj+7]=bw.w;
      if (tid < DCH) ivv[tid] = invvar[d0 + tid];
    }
    __syncthreads();
    #pragma unroll
    for (int j = 0; j < DCH; ++j) {
      float iv = ivv[j];
      float xv0 = xs[r0+0][j], xv1 = xs[r0+1][j], xv2 = xs[r0+2][j], xv3 = xs[r0+3][j];
      float wv0 = wsh[c0+0][j], wv1 = wsh[c0+1][j], wv2 = wsh[c0+2][j], wv3 = wsh[c0+3][j];
      x2a0 = fmaf(xv0, xv0*iv, x2a0);
      x2a1 = fmaf(xv1, xv1*iv, x2a1);
      x2a2 = fmaf(xv2, xv2*iv, x2a2);
      x2a3 = fmaf(xv3, xv3*iv, x2a3);
      acc00 = fmaf(xv0, wv0, acc00); acc01 = fmaf(xv0, wv1, acc01);
      acc02 = fmaf(xv0, wv2, acc02); acc03 = fmaf(xv0, wv3, acc03);
      acc10 = fmaf(xv1, wv0, acc10); acc11 = fmaf(xv1, wv1, acc11);
      acc12 = fmaf(xv1, wv2, acc12); acc13 = fmaf(xv1, wv3, acc13);
      acc20 = fmaf(xv2, wv0, acc20); acc21 = fmaf(xv2, wv1, acc21);
      acc22 = fmaf(xv2, wv2, acc22); acc23 = fmaf(xv2, wv3, acc23);
      acc30 = fmaf(xv3, wv0, acc30); acc31 = fmaf(xv3, wv1, acc31);
      acc32 = fmaf(xv3, wv2, acc32); acc33 = fmaf(xv3, wv3, acc33);
    }
  }
  float qa = q2s[c0+0], qb = q2s[c0+1], qc = q2s[c0+2], qd = q2s[c0+3];
  {
    size_t row = row0 + r0 + 0; float h = 0.5f * x2a0; float4 o;
    o.x = LOG2E*(acc00-h)+qa; o.y = LOG2E*(acc01-h)+qb; o.z = LOG2E*(acc02-h)+qc; o.w = LOG2E*(acc03-h)+qd;
    *(float4*)&em2[row*CC + c0] = o;
  }
  {
    size_t row = row0 + r0 + 1; float h = 0.5f * x2a1; float4 o;
    o.x = LOG2E*(acc10-h)+qa; o.y = LOG2E*(acc11-h)+qb; o.z = LOG2E*(acc12-h)+qc; o.w = LOG2E*(acc13-h)+qd;
    *(float4*)&em2[row*CC + c0] = o;
  }
  {
    size_t row = row0 + r0 + 2; float h = 0.5f * x2a2; float4 o;
    o.x = LOG2E*(acc20-h)+qa; o.y = LOG2E*(acc21-h)+qb; o.z = LOG2E*(acc22-h)+qc; o.w = LOG2E*(acc23-h)+qd;
    *(float4*)&em2[row*CC + c0] = o;
  }
  {
    size_t row = row0 + r0 + 3; float h = 0.5f * x2a3; float4 o;
    o.x = LOG2E*(acc30-h)+qa; o.y = LOG2E*(acc31-h)+qb; o.z = LOG2E*(acc32-h)+qc; o.w = LOG2E*(acc33-h)+qd;
    *(float4*)&em2[row*CC + c0] = o;
  }
}

// ---------------------------------------------------------------------------
// Recursion: 1 block = 1 batch, 1 wave = 64 channels.
// Pipelined: rest_{t+1} (k=2..20 duration terms) computed during step t so the
// serial chain is only: g_prev -> combine -> alpha -> DPP max -> exp2 ->
// f16 dot2 matvec -> log2 -> g. k=1 term never touches LDS.
// ---------------------------------------------------------------------------
__global__ __launch_bounds__(64, 1) void recur_kernel(
    const float* __restrict__ em2,
    const float* __restrict__ P_T,
    const float* __restrict__ init2,
    const float* __restrict__ len2,
    const int* __restrict__ lengths,
    float* __restrict__ out,
    int N) {
  __shared__ float g[64 * CC];  // doubled ring [slot 0..63][c], slot x = x&31
  int b = blockIdx.x;
  int c = threadIdx.x;  // 0..63

#if __has_builtin(__builtin_amdgcn_fdot2)
  h2 Ppk[32];
  #pragma unroll
  for (int k = 0; k < 32; ++k) {
    h2 v;
    v[0] = (_Float16)P_T[(2 * k) * CC + c];
    v[1] = (_Float16)P_T[(2 * k + 1) * CC + c];
    Ppk[k] = v;
  }
#else
  float P[CC];
  #pragma unroll
  for (int j = 0; j < CC; ++j) P[j] = P_T[j * CC + c];
#endif
  float L[KK];
  #pragma unroll
  for (int k = 0; k < KK; ++k) L[k] = len2[k * CC + c];
  float ivq = init2[c];
  #pragma unroll
  for (int s = 0; s < 64; ++s) g[s * CC + c] = (s == 0 || s == 32) ? ivq : BIGN;
  __syncthreads();
  int len_b = lengths[b];
  const float* em_b = em2 + (size_t)b * N * CC;
  float ce = 0.f;
  float em1  = em_b[c];
  float em2r = (N >= 2) ? em_b[CC + c] : 0.f;
  float g_prev = ivq;       // g_0
  float restM = BIGN, restS = 0.f;  // rest_1: empty (k>=2 all out of range)
  for (int t = 1; t <= N; ++t) {
    float em = em1;
    em1 = em2r;
    em2r = (t + 2 <= N) ? em_b[(size_t)(t + 1) * CC + c] : 0.f;
    ce += em;

    // ---- (b) rest_{t+1} over k=2..20: g_{t-1} (reg) + slots t-19..t-2 ----
    const float* p = &g[(((unsigned)(t + 13) & 31u) * CC) + c];
    float rt = g_prev + L[1];
    float rk[18];
    #pragma unroll
    for (int j = 0; j < 18; ++j) rk[j] = p[j * CC] + L[19 - j];
    float Mr = rt;
    #pragma unroll
    for (int j = 0; j < 18; ++j) Mr = fmaxf(Mr, rk[j]);
    float q0 = EXP2(rt - Mr), q1 = 0.f, q2_ = 0.f, q3 = 0.f;
    #pragma unroll
    for (int j = 0; j < 16; j += 4) {
      q0 += EXP2(rk[j]     - Mr);
      q1 += EXP2(rk[j + 1] - Mr);
      q2_ += EXP2(rk[j + 2] - Mr);
      q3 += EXP2(rk[j + 3] - Mr);
    }
    q0 += EXP2(rk[16] - Mr);
    q1 += EXP2(rk[17] - Mr);
    float Sr = (q0 + q1) + (q2_ + q3);

    // ---- (a) combine with k=1 term (register only) ----
    float tk0 = g_prev + L[0];
    float Mc = fmaxf(restM, tk0);
    float sc = restS * EXP2(restM - Mc) + EXP2(tk0 - Mc);
    float alpha = ce + Mc + LOG2(sc);

    // ---- wave max + matvec ----
    float Ma = wave_max64(alpha);
    float e = EXP2(alpha - Ma);

    if (t == len_b) {
      float se = wave_sum64(e);
      if (c == 0) out[b] = LN2 * (Ma + LOG2(se));
    }

#if __has_builtin(__builtin_amdgcn_fdot2)
    // pack (e_{2k}, e_{2k+1}) as f16x2 on even lanes, broadcast via readlane
    union { _Float16 h; unsigned short u; } cv;
    cv.h = (_Float16)e;
    int ev = (int)cv.u;
    int nb = __builtin_amdgcn_update_dpp(0, ev, 0xB1, 0xf, 0xf, true);  // lane^1
    int pk = ev | (nb << 16);
    float a0 = 0.f, a1 = 0.f, a2 = 0.f, a3 = 0.f;
    #pragma unroll
    for (int k = 0; k < 32; k += 4) {
      union { int u; h2 v; } s0, s1, s2, s3;
      s0.u = __builtin_amdgcn_readlane(pk, 2 * k);
      s1.u = __builtin_amdgcn_readlane(pk, 2 * k + 2);
      s2.u = __builtin_amdgcn_readlane(pk, 2 * k + 4);
      s3.u = __builtin_amdgcn_readlane(pk, 2 * k + 6);
      a0 = __builtin_amdgcn_fdot2(Ppk[k],     s0.v, a0, false);
      a1 = __builtin_amdgcn_fdot2(Ppk[k + 1], s1.v, a1, false);
      a2 = __builtin_amdgcn_fdot2(Ppk[k + 2], s2.v, a2, false);
      a3 = __builtin_amdgcn_fdot2(Ppk[k + 3], s3.v, a3, false);
    }
#else
    float a0 = 0.f, a1 = 0.f, a2 = 0.f, a3 = 0.f;
    #pragma unroll
    for (int j = 0; j < CC; j += 4) {
      a0 = fmaf(P[j],     rlane(e, j),     a0);
      a1 = fmaf(P[j + 1], rlane(e, j + 1), a1);
      a2 = fmaf(P[j + 2], rlane(e, j + 2), a2);
      a3 = fmaf(P[j + 3], rlane(e, j + 3), a3);
    }
#endif
    float beta = Ma + LOG2((a0 + a1) + (a2 + a3));
    float gv = beta - ce;
    int slot = t & 31;
    g[slot * CC + c] = gv;
    g[(slot + 32) * CC + c] = gv;
    g_prev = gv;
    restM = Mr;
    restS = Sr;
  }
}

extern "C" void kernel_launch(void* const* d_in, const int* in_sizes, int n_in,
                              void* d_out, int out_size, void* d_ws, size_t ws_size,
                              hipStream_t stream) {
  const float* feat   = (const float*)d_in[0];
  const int*   lens   = (const int*)d_in[1];
  const float* means  = (const float*)d_in[2];
  const float* cov    = (const float*)d_in[3];
  const float* tl     = (const float*)d_in[4];
  const float* il     = (const float*)d_in[5];
  const float* plr    = (const float*)d_in[6];
  int B = in_sizes[1];
  int D = in_sizes[2] / CC;
  int N = in_sizes[0] / (B * D);

  float* ws = (float*)d_ws;
  size_t off = 0;
  float* wmat   = ws + off; off += (size_t)CC * D;
  float* invvar = ws + off; off += D;
  float* q2     = ws + off; off += CC;
  float* P_T    = ws + off; off += CC * CC;
  float* init2  = ws + off; off += CC;
  float* len2   = ws + off; off += KK * CC;
  float* em2    = ws + off; off += (size_t)B * N * CC;

  hipLaunchKernelGGL(setup_kernel, dim3(1), dim3(256), 0, stream,
                     means, cov, tl, il, plr, wmat, invvar, q2, P_T, init2, len2, D);
  hipLaunchKernelGGL(emission_kernel, dim3((B * N) / 64), dim3(256), 0, stream,
                     feat, wmat, invvar, q2, em2, D);
  hipLaunchKernelGGL(recur_kernel, dim3(B), dim3(64), 0, stream,
                     em2, P_T, init2, len2, lens, (float*)d_out, N);
}